// Round 3
// baseline (477.166 us; speedup 1.0000x reference)
//
#include <hip/hip_runtime.h>
#include <hip/hip_bf16.h>

#define BB 4
#define SS 2048
#define HH 576
#define NHD 9
#define NKVH 3
#define HDIM 64

using s8v = __attribute__((ext_vector_type(8))) short;
using f4v = __attribute__((ext_vector_type(4))) float;

__device__ __forceinline__ unsigned short f2bf(float f) {
  union { float f; unsigned u; } x; x.f = f;
  unsigned r = x.u + 0x7fffu + ((x.u >> 16) & 1u);
  return (unsigned short)(r >> 16);
}

__device__ __forceinline__ float bf2f(unsigned short u) {
  union { unsigned u; float f; } x; x.u = ((unsigned)u) << 16;
  return x.f;
}

__device__ __forceinline__ unsigned pk2bf(float lo, float hi) {
  union { __hip_bfloat162 h; unsigned u; } c;
  c.h = __float22bfloat162_rn(make_float2(lo, hi));
  return c.u;
}

__device__ __forceinline__ float fexp2(float x) {
#if __has_builtin(__builtin_amdgcn_exp2f)
  return __builtin_amdgcn_exp2f(x);
#else
  return exp2f(x);
#endif
}

// Q pre-scale: (1/sqrt(64)) * log2(e)  -> softmax runs in exp2 domain
#define QSCALE 0.1803368867f

// ---------------- kernel 1: cast hidden_states fp32 -> bf16 ----------------
__global__ void cast_x_kernel(const float* __restrict__ hs, unsigned short* __restrict__ xb) {
  long i = (long)blockIdx.x * blockDim.x + threadIdx.x;
  long base = i * 4;
  float4 v = *(const float4*)(hs + base);
  ushort4 o;
  o.x = f2bf(v.x); o.y = f2bf(v.y); o.z = f2bf(v.z); o.w = f2bf(v.w);
  *(ushort4*)(xb + base) = o;
}

// ------------- kernel 2: pack weights -> bf16, transposed [n][k] -----------
__global__ void pack_w_kernel(const float* __restrict__ wq, const float* __restrict__ wk,
                              const float* __restrict__ wv, const float* __restrict__ wo,
                              unsigned short* __restrict__ wqkvt, unsigned short* __restrict__ wot) {
  int i = blockIdx.x * blockDim.x + threadIdx.x;
  if (i < 960 * 576) {
    int n = i / 576, k = i % 576;
    float val;
    if (n < 576)      val = wq[k * 576 + n];
    else if (n < 768) val = wk[k * 192 + (n - 576)];
    else              val = wv[k * 192 + (n - 768)];
    wqkvt[n * 576 + k] = f2bf(val);
  } else {
    int j = i - 960 * 576;
    int n = j / 576, k = j % 576;
    wot[n * 576 + k] = f2bf(wo[k * 576 + n]);
  }
}

// ---- kernel 3: QKV GEMM (bf16 MFMA) + fused RoPE; writes Q,K,[Vt] bf16 ----
// Q is pre-scaled by QSCALE (softmax in exp2 domain).
__global__ __launch_bounds__(256) void qkv_gemm_kernel(
    const unsigned short* __restrict__ xb, const unsigned short* __restrict__ wt,
    const float* __restrict__ rot,
    unsigned short* __restrict__ qbuf, unsigned short* __restrict__ kbuf,
    unsigned short* __restrict__ vtbuf)
{
  const int lane = threadIdx.x & 63;
  const int wid  = threadIdx.x >> 6;
  const int l15 = lane & 15, hi = lane >> 4;
  const int m0 = blockIdx.x * 64 + wid * 16;
  const int g  = blockIdx.y;
  const int n0 = g * 64;

  const f4v zero = {0.f, 0.f, 0.f, 0.f};
  f4v acc[4] = {zero, zero, zero, zero};

  for (int kk = 0; kk < 18; ++kk) {
    const int k0 = kk * 32 + hi * 8;
    s8v a = *(const s8v*)(xb + (long)(m0 + l15) * 576 + k0);
#pragma unroll
    for (int nb = 0; nb < 4; ++nb) {
      s8v b = *(const s8v*)(wt + (long)(n0 + nb * 16 + l15) * 576 + k0);
      acc[nb] = __builtin_amdgcn_mfma_f32_16x16x32_bf16(a, b, acc[nb], 0, 0, 0);
    }
  }

  const int row_base = m0 + hi * 4;
  if (g < 12) {  // RoPE (pairs d <-> d+32 live in nb <-> nb+2, same lane)
#pragma unroll
    for (int r = 0; r < 4; ++r) {
      const int s = (row_base + r) & (SS - 1);
#pragma unroll
      for (int nb = 0; nb < 2; ++nb) {
        const int d = l15 + nb * 16;
        const float sn = rot[s * 64 + d];
        const float cs = rot[s * 64 + 32 + d];
        const float x1 = acc[nb][r], x2 = acc[nb + 2][r];
        acc[nb][r]     = x1 * cs - x2 * sn;
        acc[nb + 2][r] = x1 * sn + x2 * cs;
      }
    }
  }

  if (g < 9) {            // Q head (scaled by QSCALE)
    const int h = g;
#pragma unroll
    for (int r = 0; r < 4; ++r) {
      const int row = row_base + r, b = row >> 11, s = row & (SS - 1);
      unsigned short* dst = qbuf + ((long)((b * NHD + h) * SS + s)) * HDIM;
#pragma unroll
      for (int nb = 0; nb < 4; ++nb) dst[l15 + nb * 16] = f2bf(acc[nb][r] * QSCALE);
    }
  } else if (g < 12) {    // K head
    const int h = g - 9;
#pragma unroll
    for (int r = 0; r < 4; ++r) {
      const int row = row_base + r, b = row >> 11, s = row & (SS - 1);
      unsigned short* dst = kbuf + ((long)((b * NKVH + h) * SS + s)) * HDIM;
#pragma unroll
      for (int nb = 0; nb < 4; ++nb) dst[l15 + nb * 16] = f2bf(acc[nb][r]);
    }
  } else {                // V head -> transposed [b][h][d][s]
    const int h = g - 12;
#pragma unroll
    for (int r = 0; r < 4; ++r) {
      const int row = row_base + r, b = row >> 11, s = row & (SS - 1);
#pragma unroll
      for (int nb = 0; nb < 4; ++nb) {
        const int d = l15 + nb * 16;
        vtbuf[((long)((b * NKVH + h) * HDIM + d)) * SS + s] = f2bf(acc[nb][r]);
      }
    }
  }
}

// ------- kernel 4a: split-KV flash. 1 wave = 16 q rows x one 512-kv chunk ---
// Work decode: wgid -> (bh, w); w = 319 - wgid/36 descending; w -> (qs, c).
// Writes unnormalized partials: m,l (f32) + O (bf16) per wave.
__global__ __launch_bounds__(256, 8) void flash_split_kernel(
    const unsigned short* __restrict__ qbuf, const unsigned short* __restrict__ kbuf,
    const unsigned short* __restrict__ vtbuf,
    float* __restrict__ mlpart, unsigned short* __restrict__ opart)
{
  const int lane = threadIdx.x & 63, wid = threadIdx.x >> 6;
  const int l15 = lane & 15, hi = lane >> 4;
  const int wgid = blockIdx.x * 4 + wid;          // 0..11519
  const int bh = wgid % 36;
  const int w  = 319 - wgid / 36;                 // descending work size
  int qs, c;
  if (w < 32)       { qs = w;                 c = 0; }
  else if (w < 96)  { int t = w - 32;  qs = 32 + (t >> 1); c = t & 1; }
  else if (w < 192) { int t = w - 96;  int d3 = t / 3; qs = 64 + d3; c = t - 3 * d3; }
  else              { int t = w - 192; qs = 96 + (t >> 2); c = t & 3; }
  const int q0 = qs * 16;
  const int kb0 = c * 512;
  const int kend = min(kb0 + 512, q0 + 16);
  const int b = bh / NHD, h = bh % NHD;
  const int hkv = h / 3;

  const unsigned short* Q  = qbuf + ((long)(b * NHD + h) * SS) * HDIM;
  const unsigned short* K  = kbuf + ((long)(b * NKVH + hkv) * SS) * HDIM;
  const unsigned short* Vt = vtbuf + ((long)(b * NKVH + hkv) * HDIM) * SS;

  const s8v qb0 = *(const s8v*)(Q + (long)(q0 + l15) * HDIM + hi * 8);
  const s8v qb1 = *(const s8v*)(Q + (long)(q0 + l15) * HDIM + 32 + hi * 8);

  const f4v zero = {0.f, 0.f, 0.f, 0.f};
  f4v accO[4] = {zero, zero, zero, zero};
  float m_run = -1e30f, l_run = 0.f;

  const int srcA = l15 + ((hi & 1) << 5);
  const int srcB = srcA + 16;
  const bool hih = hi >= 2;

  s8v ka0 = *(const s8v*)(K + (long)(kb0 + l15) * HDIM + hi * 8);
  s8v ka1 = *(const s8v*)(K + (long)(kb0 + l15) * HDIM + 32 + hi * 8);
  s8v ka2 = *(const s8v*)(K + (long)(kb0 + 16 + l15) * HDIM + hi * 8);
  s8v ka3 = *(const s8v*)(K + (long)(kb0 + 16 + l15) * HDIM + 32 + hi * 8);

  for (int kv0 = kb0; kv0 < kend; kv0 += 32) {
    f4v s0 = __builtin_amdgcn_mfma_f32_16x16x32_bf16(ka0, qb0, zero, 0, 0, 0);
    s0     = __builtin_amdgcn_mfma_f32_16x16x32_bf16(ka1, qb1, s0,   0, 0, 0);
    f4v s1 = __builtin_amdgcn_mfma_f32_16x16x32_bf16(ka2, qb0, zero, 0, 0, 0);
    s1     = __builtin_amdgcn_mfma_f32_16x16x32_bf16(ka3, qb1, s1,   0, 0, 0);

    {  // prefetch next K tile (over-read stays inside workspace)
      const unsigned short* Kn = K + (long)(kv0 + 32) * HDIM;
      ka0 = *(const s8v*)(Kn + (long)(l15) * HDIM + hi * 8);
      ka1 = *(const s8v*)(Kn + (long)(l15) * HDIM + 32 + hi * 8);
      ka2 = *(const s8v*)(Kn + (long)(16 + l15) * HDIM + hi * 8);
      ka3 = *(const s8v*)(Kn + (long)(16 + l15) * HDIM + 32 + hi * 8);
    }
    const s8v va0 = *(const s8v*)(Vt + (long)( 0 + l15) * SS + kv0 + hi * 8);
    const s8v va1 = *(const s8v*)(Vt + (long)(16 + l15) * SS + kv0 + hi * 8);
    const s8v va2 = *(const s8v*)(Vt + (long)(32 + l15) * SS + kv0 + hi * 8);
    const s8v va3 = *(const s8v*)(Vt + (long)(48 + l15) * SS + kv0 + hi * 8);

    float a0[4], a1[4];
#pragma unroll
    for (int r = 0; r < 4; ++r) { a0[r] = s0[r]; a1[r] = s1[r]; }
    if (kv0 + 31 > q0) {  // causal boundary tile
      const int qrel = q0 + l15 - kv0;
#pragma unroll
      for (int r = 0; r < 4; ++r) {
        a0[r] = (hi * 4 + r      <= qrel) ? a0[r] : -1e30f;
        a1[r] = (hi * 4 + r + 16 <= qrel) ? a1[r] : -1e30f;
      }
    }
    float mloc = fmaxf(fmaxf(fmaxf(a0[0], a0[1]), fmaxf(a0[2], a0[3])),
                       fmaxf(fmaxf(a1[0], a1[1]), fmaxf(a1[2], a1[3])));
    mloc = fmaxf(mloc, __shfl_xor(mloc, 16));
    mloc = fmaxf(mloc, __shfl_xor(mloc, 32));
    if (__any(mloc > m_run + 8.f)) {   // defer-max (THR=8 in log2 units)
      const float mnew = fmaxf(m_run, mloc);
      const float corr = fexp2(m_run - mnew);
      m_run = mnew;
      l_run *= corr;
#pragma unroll
      for (int t = 0; t < 4; ++t) accO[t] *= corr;
    }
    float p0[4], p1[4], sloc = 0.f;
#pragma unroll
    for (int r = 0; r < 4; ++r) {
      p0[r] = fexp2(a0[r] - m_run);
      p1[r] = fexp2(a1[r] - m_run);
      sloc += p0[r] + p1[r];
    }
    sloc += __shfl_xor(sloc, 16);
    sloc += __shfl_xor(sloc, 32);
    l_run += sloc;

    const unsigned u0 = pk2bf(p0[0], p0[1]);
    const unsigned u1 = pk2bf(p0[2], p0[3]);
    const unsigned u2 = pk2bf(p1[0], p1[1]);
    const unsigned u3 = pk2bf(p1[2], p1[3]);
    const unsigned xa0 = __shfl(u0, srcA), xa1 = __shfl(u1, srcA);
    const unsigned xa2 = __shfl(u2, srcA), xa3 = __shfl(u3, srcA);
    const unsigned xb0 = __shfl(u0, srcB), xb1 = __shfl(u1, srcB);
    const unsigned xb2 = __shfl(u2, srcB), xb3 = __shfl(u3, srcB);
    union { unsigned u[4]; s8v v; } pbu;
    pbu.u[0] = hih ? xa2 : xa0;
    pbu.u[1] = hih ? xa3 : xa1;
    pbu.u[2] = hih ? xb2 : xb0;
    pbu.u[3] = hih ? xb3 : xb1;
    const s8v pb = pbu.v;

    accO[0] = __builtin_amdgcn_mfma_f32_16x16x32_bf16(va0, pb, accO[0], 0, 0, 0);
    accO[1] = __builtin_amdgcn_mfma_f32_16x16x32_bf16(va1, pb, accO[1], 0, 0, 0);
    accO[2] = __builtin_amdgcn_mfma_f32_16x16x32_bf16(va2, pb, accO[2], 0, 0, 0);
    accO[3] = __builtin_amdgcn_mfma_f32_16x16x32_bf16(va3, pb, accO[3], 0, 0, 0);
  }

  // write partials (storage index = wgid)
  if (hi == 0) {
    float* ml = mlpart + (long)wgid * 32;
    ml[l15]      = m_run;
    ml[16 + l15] = l_run;
  }
  unsigned short* op = opart + (long)wgid * 1024;
#pragma unroll
  for (int t = 0; t < 4; ++t) {
    ushort4 o;
    o.x = f2bf(accO[t][0]);
    o.y = f2bf(accO[t][1]);
    o.z = f2bf(accO[t][2]);
    o.w = f2bf(accO[t][3]);
    *(ushort4*)(op + l15 * 64 + t * 16 + hi * 4) = o;
  }
}

// ---------- kernel 4b: combine partials -> normalized obuf (bf16) ----------
// 1 block = one (bh, qs) q-tile; 256 threads = 16 q x 16 d-quads.
__global__ __launch_bounds__(256) void combine_kernel(
    const float* __restrict__ mlpart, const unsigned short* __restrict__ opart,
    unsigned short* __restrict__ obuf)
{
  const int bid = blockIdx.x;           // 0..4607
  const int bh = bid % 36, qs = bid / 36;
  const int b = bh / NHD, h = bh % NHD;
  int nc, base;
  if (qs < 32)      { nc = 1; base = qs; }
  else if (qs < 64) { nc = 2; base = 32 + 2 * (qs - 32); }
  else if (qs < 96) { nc = 3; base = 96 + 3 * (qs - 64); }
  else              { nc = 4; base = 192 + 4 * (qs - 96); }

  const int t = threadIdx.x;
  const int q = t >> 4, d0 = (t & 15) * 4;

  int idx[4]; float m[4], l[4];
  float M = -1e30f;
  for (int cc = 0; cc < nc; ++cc) {
    idx[cc] = (319 - (base + cc)) * 36 + bh;
    m[cc] = mlpart[(long)idx[cc] * 32 + q];
    l[cc] = mlpart[(long)idx[cc] * 32 + 16 + q];
    M = fmaxf(M, m[cc]);
  }
  float L = 0.f, acc0 = 0.f, acc1 = 0.f, acc2 = 0.f, acc3 = 0.f;
  for (int cc = 0; cc < nc; ++cc) {
    const float wgt = fexp2(m[cc] - M);
    L += l[cc] * wgt;
    ushort4 v = *(const ushort4*)(opart + (long)idx[cc] * 1024 + q * 64 + d0);
    acc0 += wgt * bf2f(v.x);
    acc1 += wgt * bf2f(v.y);
    acc2 += wgt * bf2f(v.z);
    acc3 += wgt * bf2f(v.w);
  }
  const float inv = 1.f / L;
  ushort4 o;
  o.x = f2bf(acc0 * inv);
  o.y = f2bf(acc1 * inv);
  o.z = f2bf(acc2 * inv);
  o.w = f2bf(acc3 * inv);
  *(ushort4*)(obuf + (long)(b * SS + qs * 16 + q) * HH + h * HDIM + d0) = o;
}

// ------- kernel 4-fallback: R1 flash (exp2 domain), if ws too small --------
__global__ __launch_bounds__(128, 4) void flash_fb_kernel(
    const unsigned short* __restrict__ qbuf, const unsigned short* __restrict__ kbuf,
    const unsigned short* __restrict__ vtbuf, unsigned short* __restrict__ obuf)
{
  const int lane = threadIdx.x & 63, wid = threadIdx.x >> 6;
  const int l15 = lane & 15, hi = lane >> 4;
  const int widx = blockIdx.x * 2 + wid;
  const int qs = 127 - widx / 36;
  const int bh = widx % 36;
  const int q0 = qs * 16;
  const int b = bh / NHD, h = bh % NHD;
  const int hkv = h / 3;

  const unsigned short* Q  = qbuf + ((long)(b * NHD + h) * SS) * HDIM;
  const unsigned short* K  = kbuf + ((long)(b * NKVH + hkv) * SS) * HDIM;
  const unsigned short* Vt = vtbuf + ((long)(b * NKVH + hkv) * HDIM) * SS;

  const s8v qb0 = *(const s8v*)(Q + (long)(q0 + l15) * HDIM + hi * 8);
  const s8v qb1 = *(const s8v*)(Q + (long)(q0 + l15) * HDIM + 32 + hi * 8);

  const f4v zero = {0.f, 0.f, 0.f, 0.f};
  f4v accO[4] = {zero, zero, zero, zero};
  float m_run = -1e30f, l_run = 0.f;

  const int srcA = l15 + ((hi & 1) << 5);
  const int srcB = srcA + 16;
  const bool hih = hi >= 2;

  s8v ka0 = *(const s8v*)(K + (long)(l15) * HDIM + hi * 8);
  s8v ka1 = *(const s8v*)(K + (long)(l15) * HDIM + 32 + hi * 8);
  s8v ka2 = *(const s8v*)(K + (long)(16 + l15) * HDIM + hi * 8);
  s8v ka3 = *(const s8v*)(K + (long)(16 + l15) * HDIM + 32 + hi * 8);

  const int kv_end = q0 + 16;
  for (int kv0 = 0; kv0 < kv_end; kv0 += 32) {
    f4v s0 = __builtin_amdgcn_mfma_f32_16x16x32_bf16(ka0, qb0, zero, 0, 0, 0);
    s0     = __builtin_amdgcn_mfma_f32_16x16x32_bf16(ka1, qb1, s0,   0, 0, 0);
    f4v s1 = __builtin_amdgcn_mfma_f32_16x16x32_bf16(ka2, qb0, zero, 0, 0, 0);
    s1     = __builtin_amdgcn_mfma_f32_16x16x32_bf16(ka3, qb1, s1,   0, 0, 0);
    {
      const unsigned short* Kn = K + (long)(kv0 + 32) * HDIM;
      ka0 = *(const s8v*)(Kn + (long)(l15) * HDIM + hi * 8);
      ka1 = *(const s8v*)(Kn + (long)(l15) * HDIM + 32 + hi * 8);
      ka2 = *(const s8v*)(Kn + (long)(16 + l15) * HDIM + hi * 8);
      ka3 = *(const s8v*)(Kn + (long)(16 + l15) * HDIM + 32 + hi * 8);
    }
    const s8v va0 = *(const s8v*)(Vt + (long)( 0 + l15) * SS + kv0 + hi * 8);
    const s8v va1 = *(const s8v*)(Vt + (long)(16 + l15) * SS + kv0 + hi * 8);
    const s8v va2 = *(const s8v*)(Vt + (long)(32 + l15) * SS + kv0 + hi * 8);
    const s8v va3 = *(const s8v*)(Vt + (long)(48 + l15) * SS + kv0 + hi * 8);

    float a0[4], a1[4];
#pragma unroll
    for (int r = 0; r < 4; ++r) { a0[r] = s0[r]; a1[r] = s1[r]; }
    if (kv0 + 31 > q0) {
      const int qrel = q0 + l15 - kv0;
#pragma unroll
      for (int r = 0; r < 4; ++r) {
        a0[r] = (hi * 4 + r      <= qrel) ? a0[r] : -1e30f;
        a1[r] = (hi * 4 + r + 16 <= qrel) ? a1[r] : -1e30f;
      }
    }
    float mloc = fmaxf(fmaxf(fmaxf(a0[0], a0[1]), fmaxf(a0[2], a0[3])),
                       fmaxf(fmaxf(a1[0], a1[1]), fmaxf(a1[2], a1[3])));
    mloc = fmaxf(mloc, __shfl_xor(mloc, 16));
    mloc = fmaxf(mloc, __shfl_xor(mloc, 32));
    if (__any(mloc > m_run + 8.f)) {
      const float mnew = fmaxf(m_run, mloc);
      const float corr = fexp2(m_run - mnew);
      m_run = mnew;
      l_run *= corr;
#pragma unroll
      for (int t = 0; t < 4; ++t) accO[t] *= corr;
    }
    float p0[4], p1[4], sloc = 0.f;
#pragma unroll
    for (int r = 0; r < 4; ++r) {
      p0[r] = fexp2(a0[r] - m_run);
      p1[r] = fexp2(a1[r] - m_run);
      sloc += p0[r] + p1[r];
    }
    sloc += __shfl_xor(sloc, 16);
    sloc += __shfl_xor(sloc, 32);
    l_run += sloc;

    const unsigned u0 = pk2bf(p0[0], p0[1]);
    const unsigned u1 = pk2bf(p0[2], p0[3]);
    const unsigned u2 = pk2bf(p1[0], p1[1]);
    const unsigned u3 = pk2bf(p1[2], p1[3]);
    const unsigned xa0 = __shfl(u0, srcA), xa1 = __shfl(u1, srcA);
    const unsigned xa2 = __shfl(u2, srcA), xa3 = __shfl(u3, srcA);
    const unsigned xb0 = __shfl(u0, srcB), xb1 = __shfl(u1, srcB);
    const unsigned xb2 = __shfl(u2, srcB), xb3 = __shfl(u3, srcB);
    union { unsigned u[4]; s8v v; } pbu;
    pbu.u[0] = hih ? xa2 : xa0;
    pbu.u[1] = hih ? xa3 : xa1;
    pbu.u[2] = hih ? xb2 : xb0;
    pbu.u[3] = hih ? xb3 : xb1;
    const s8v pb = pbu.v;

    accO[0] = __builtin_amdgcn_mfma_f32_16x16x32_bf16(va0, pb, accO[0], 0, 0, 0);
    accO[1] = __builtin_amdgcn_mfma_f32_16x16x32_bf16(va1, pb, accO[1], 0, 0, 0);
    accO[2] = __builtin_amdgcn_mfma_f32_16x16x32_bf16(va2, pb, accO[2], 0, 0, 0);
    accO[3] = __builtin_amdgcn_mfma_f32_16x16x32_bf16(va3, pb, accO[3], 0, 0, 0);
  }

  const float inv = 1.f / l_run;
  const int s = q0 + l15;
#pragma unroll
  for (int t = 0; t < 4; ++t) {
    ushort4 o;
    o.x = f2bf(accO[t][0] * inv);
    o.y = f2bf(accO[t][1] * inv);
    o.z = f2bf(accO[t][2] * inv);
    o.w = f2bf(accO[t][3] * inv);
    *(ushort4*)(obuf + (long)(b * SS + s) * HH + h * HDIM + t * 16 + hi * 4) = o;
  }
}

// ----------------- kernel 5: output projection -> fp32 d_out ----------------
__global__ __launch_bounds__(256) void out_gemm_kernel(
    const unsigned short* __restrict__ ob, const unsigned short* __restrict__ wot,
    float* __restrict__ out)
{
  const int lane = threadIdx.x & 63;
  const int wid  = threadIdx.x >> 6;
  const int l15 = lane & 15, hi = lane >> 4;
  const int m0 = blockIdx.x * 64 + wid * 16;
  const int n0 = blockIdx.y * 64;

  const f4v zero = {0.f, 0.f, 0.f, 0.f};
  f4v acc[4] = {zero, zero, zero, zero};

  for (int kk = 0; kk < 18; ++kk) {
    const int k0 = kk * 32 + hi * 8;
    s8v a = *(const s8v*)(ob + (long)(m0 + l15) * 576 + k0);
#pragma unroll
    for (int nb = 0; nb < 4; ++nb) {
      s8v b = *(const s8v*)(wot + (long)(n0 + nb * 16 + l15) * 576 + k0);
      acc[nb] = __builtin_amdgcn_mfma_f32_16x16x32_bf16(a, b, acc[nb], 0, 0, 0);
    }
  }
#pragma unroll
  for (int r = 0; r < 4; ++r) {
    const int row = m0 + hi * 4 + r;
#pragma unroll
    for (int nb = 0; nb < 4; ++nb) {
      out[(long)row * 576 + n0 + nb * 16 + l15] = acc[nb][r];
    }
  }
}

extern "C" void kernel_launch(void* const* d_in, const int* in_sizes, int n_in,
                              void* d_out, int out_size, void* d_ws, size_t ws_size,
                              hipStream_t stream) {
  const float* hs  = (const float*)d_in[0];
  const float* rot = (const float*)d_in[2];
  const float* wq  = (const float*)d_in[3];
  const float* wk  = (const float*)d_in[4];
  const float* wv  = (const float*)d_in[5];
  const float* wo  = (const float*)d_in[6];
  float* out = (float*)d_out;

  char* ws = (char*)d_ws;
  unsigned short* xb    = (unsigned short*)(ws + 0);          // 9,437,184
  unsigned short* wqkvt = (unsigned short*)(ws + 9437184);    // 1,105,920
  unsigned short* wot   = (unsigned short*)(ws + 10543104);   //   663,552
  unsigned short* qb    = (unsigned short*)(ws + 11206656);   // 9,437,184
  unsigned short* kb    = (unsigned short*)(ws + 20643840);   // 3,145,728
  unsigned short* vt    = (unsigned short*)(ws + 23789568);   // 3,145,728
  unsigned short* obuf  = (unsigned short*)(ws + 26935296);   // 9,437,184 -> 36,372,480
  float*          mlp   = (float*)(ws + 36372480);            // 1,474,560 -> 37,847,040
  unsigned short* opart = (unsigned short*)(ws + 37847040);   // 23,592,960 -> 61,440,000

  cast_x_kernel<<<4608, 256, 0, stream>>>(hs, xb);
  pack_w_kernel<<<3456, 256, 0, stream>>>(wq, wk, wv, wo, wqkvt, wot);
  qkv_gemm_kernel<<<dim3(128, 15), 256, 0, stream>>>(xb, wqkvt, rot, qb, kb, vt);
  if (ws_size >= (size_t)61440000) {
    flash_split_kernel<<<2880, 256, 0, stream>>>(qb, kb, vt, mlp, opart);
    combine_kernel<<<4608, 256, 0, stream>>>(mlp, opart, obuf);
  } else {
    flash_fb_kernel<<<2304, 128, 0, stream>>>(qb, kb, vt, obuf);
  }
  out_gemm_kernel<<<dim3(128, 9), 256, 0, stream>>>(obuf, wot, out);
}

// Round 4
// 240.097 us; speedup vs baseline: 1.9874x; 1.9874x over previous
//
#include <hip/hip_runtime.h>
#include <hip/hip_bf16.h>

#define BB 4
#define SS 2048
#define HH 576
#define NHD 9
#define NKVH 3
#define HDIM 64

using s8v  = __attribute__((ext_vector_type(8))) short;
using f4v  = __attribute__((ext_vector_type(4))) float;
using f16v = __attribute__((ext_vector_type(16))) float;

__device__ __forceinline__ unsigned short f2bf(float f) {
  union { float f; unsigned u; } x; x.f = f;
  unsigned r = x.u + 0x7fffu + ((x.u >> 16) & 1u);
  return (unsigned short)(r >> 16);
}

__device__ __forceinline__ unsigned pk2bf(float lo, float hi) {
  union { __hip_bfloat162 h; unsigned u; } c;
  c.h = __float22bfloat162_rn(make_float2(lo, hi));
  return c.u;
}

__device__ __forceinline__ float fexp2(float x) {
#if __has_builtin(__builtin_amdgcn_exp2f)
  return __builtin_amdgcn_exp2f(x);
#else
  return exp2f(x);
#endif
}

// Q pre-scale: (1/sqrt(64)) * log2(e) -> softmax runs in exp2 domain
#define QSCALE 0.1803368867f

// ---------------- kernel 1: cast hidden_states fp32 -> bf16 ----------------
__global__ void cast_x_kernel(const float* __restrict__ hs, unsigned short* __restrict__ xb) {
  long i = (long)blockIdx.x * blockDim.x + threadIdx.x;
  long base = i * 4;
  float4 v = *(const float4*)(hs + base);
  ushort4 o;
  o.x = f2bf(v.x); o.y = f2bf(v.y); o.z = f2bf(v.z); o.w = f2bf(v.w);
  *(ushort4*)(xb + base) = o;
}

// ------------- kernel 2: pack weights -> bf16, transposed [n][k] -----------
__global__ void pack_w_kernel(const float* __restrict__ wq, const float* __restrict__ wk,
                              const float* __restrict__ wv, const float* __restrict__ wo,
                              unsigned short* __restrict__ wqkvt, unsigned short* __restrict__ wot) {
  int i = blockIdx.x * blockDim.x + threadIdx.x;
  if (i < 960 * 576) {
    int n = i / 576, k = i % 576;
    float val;
    if (n < 576)      val = wq[k * 576 + n];
    else if (n < 768) val = wk[k * 192 + (n - 576)];
    else              val = wv[k * 192 + (n - 768)];
    wqkvt[n * 576 + k] = f2bf(val);
  } else {
    int j = i - 960 * 576;
    int n = j / 576, k = j % 576;
    wot[n * 576 + k] = f2bf(wo[k * 576 + n]);
  }
}

// ---- kernel 3: QKV GEMM (bf16 MFMA) + fused RoPE; writes Q,K,[Vt] bf16 ----
__global__ __launch_bounds__(256) void qkv_gemm_kernel(
    const unsigned short* __restrict__ xb, const unsigned short* __restrict__ wt,
    const float* __restrict__ rot,
    unsigned short* __restrict__ qbuf, unsigned short* __restrict__ kbuf,
    unsigned short* __restrict__ vtbuf)
{
  const int lane = threadIdx.x & 63;
  const int wid  = threadIdx.x >> 6;
  const int l15 = lane & 15, hi = lane >> 4;
  const int m0 = blockIdx.x * 64 + wid * 16;
  const int g  = blockIdx.y;
  const int n0 = g * 64;

  const f4v zero = {0.f, 0.f, 0.f, 0.f};
  f4v acc[4] = {zero, zero, zero, zero};

  for (int kk = 0; kk < 18; ++kk) {
    const int k0 = kk * 32 + hi * 8;
    s8v a = *(const s8v*)(xb + (long)(m0 + l15) * 576 + k0);
#pragma unroll
    for (int nb = 0; nb < 4; ++nb) {
      s8v b = *(const s8v*)(wt + (long)(n0 + nb * 16 + l15) * 576 + k0);
      acc[nb] = __builtin_amdgcn_mfma_f32_16x16x32_bf16(a, b, acc[nb], 0, 0, 0);
    }
  }

  const int row_base = m0 + hi * 4;
  if (g < 12) {  // RoPE (pairs d <-> d+32 live in nb <-> nb+2, same lane)
#pragma unroll
    for (int r = 0; r < 4; ++r) {
      const int s = (row_base + r) & (SS - 1);
#pragma unroll
      for (int nb = 0; nb < 2; ++nb) {
        const int d = l15 + nb * 16;
        const float sn = rot[s * 64 + d];
        const float cs = rot[s * 64 + 32 + d];
        const float x1 = acc[nb][r], x2 = acc[nb + 2][r];
        acc[nb][r]     = x1 * cs - x2 * sn;
        acc[nb + 2][r] = x1 * sn + x2 * cs;
      }
    }
  }

  if (g < 9) {            // Q head (scaled by QSCALE)
    const int h = g;
#pragma unroll
    for (int r = 0; r < 4; ++r) {
      const int row = row_base + r, b = row >> 11, s = row & (SS - 1);
      unsigned short* dst = qbuf + ((long)((b * NHD + h) * SS + s)) * HDIM;
#pragma unroll
      for (int nb = 0; nb < 4; ++nb) dst[l15 + nb * 16] = f2bf(acc[nb][r] * QSCALE);
    }
  } else if (g < 12) {    // K head
    const int h = g - 9;
#pragma unroll
    for (int r = 0; r < 4; ++r) {
      const int row = row_base + r, b = row >> 11, s = row & (SS - 1);
      unsigned short* dst = kbuf + ((long)((b * NKVH + h) * SS + s)) * HDIM;
#pragma unroll
      for (int nb = 0; nb < 4; ++nb) dst[l15 + nb * 16] = f2bf(acc[nb][r]);
    }
  } else {                // V head -> transposed [b][h][d][s]
    const int h = g - 12;
#pragma unroll
    for (int r = 0; r < 4; ++r) {
      const int row = row_base + r, b = row >> 11, s = row & (SS - 1);
#pragma unroll
      for (int nb = 0; nb < 4; ++nb) {
        const int d = l15 + nb * 16;
        vtbuf[((long)((b * NKVH + h) * HDIM + d)) * SS + s] = f2bf(acc[nb][r]);
      }
    }
  }
}

// ------ kernel 4: flash attention, 32x32x16 MFMA, swapped QK^T -------------
// 1 wave = 32 q-rows (q = q0 + l31 via B-frag cols), KV tile = 32. No LDS.
// Softmax fully lane-local: 15 in-lane ops + ONE shfl_xor(32) per reduce.
// P -> PV B-frag: 8 cvt_pk + 8 independent shfl_xor(32).
// grid: 1152 blocks x 128 threads (2 waves), descending-work order.
__global__ __launch_bounds__(128) void flash32_kernel(
    const unsigned short* __restrict__ qbuf, const unsigned short* __restrict__ kbuf,
    const unsigned short* __restrict__ vtbuf, unsigned short* __restrict__ obuf)
{
  const int lane = threadIdx.x & 63, wid = threadIdx.x >> 6;
  const int l31 = lane & 31, hi = lane >> 5;
  const int widx = blockIdx.x * 2 + wid;          // 0..2303
  const int qs = 63 - widx / 36;                  // descending work
  const int bh = widx % 36;
  const int q0 = qs * 32;
  const int b = bh / NHD, h = bh % NHD;
  const int hkv = h / 3;

  const unsigned short* Q  = qbuf + ((long)(b * NHD + h) * SS) * HDIM;
  const unsigned short* K  = kbuf + ((long)(b * NKVH + hkv) * SS) * HDIM;
  const unsigned short* Vt = vtbuf + ((long)(b * NKVH + hkv) * HDIM) * SS;

  // Q B-frags: col q = q0+l31, k(d) = ks*16 + hi*8 + j
  s8v qf[4];
#pragma unroll
  for (int ks = 0; ks < 4; ++ks)
    qf[ks] = *(const s8v*)(Q + (long)(q0 + l31) * HDIM + ks * 16 + hi * 8);

  f16v accO0 = {}, accO1 = {};
  float m_run = -1e30f, l_run = 0.f;

  // preload K A-frags for tile 0: row kv = l31, k(d) = ks*16 + hi*8 + j
  s8v kf[4];
#pragma unroll
  for (int ks = 0; ks < 4; ++ks)
    kf[ks] = *(const s8v*)(K + (long)(l31) * HDIM + ks * 16 + hi * 8);

  for (int kv0 = 0; kv0 <= q0; kv0 += 32) {
    // S[kv][q]: A = K (rows kv), B = Q (cols q); 4 chained k-steps over d=64
    f16v S = {};
    S = __builtin_amdgcn_mfma_f32_32x32x16_bf16(kf[0], qf[0], S, 0, 0, 0);
    S = __builtin_amdgcn_mfma_f32_32x32x16_bf16(kf[1], qf[1], S, 0, 0, 0);
    S = __builtin_amdgcn_mfma_f32_32x32x16_bf16(kf[2], qf[2], S, 0, 0, 0);
    S = __builtin_amdgcn_mfma_f32_32x32x16_bf16(kf[3], qf[3], S, 0, 0, 0);

    // prefetch next K tile (over-read past end stays inside workspace)
    {
      const unsigned short* Kn = K + (long)(kv0 + 32 + l31) * HDIM;
#pragma unroll
      for (int ks = 0; ks < 4; ++ks)
        kf[ks] = *(const s8v*)(Kn + ks * 16 + hi * 8);
    }
    // V A-frags, issue early: row d = dh*32 + l31, k(kv) = ks*16 + hi*8 + j
    s8v vf00 = *(const s8v*)(Vt + (long)(l31) * SS      + kv0 + hi * 8);
    s8v vf01 = *(const s8v*)(Vt + (long)(l31) * SS      + kv0 + 16 + hi * 8);
    s8v vf10 = *(const s8v*)(Vt + (long)(32 + l31) * SS + kv0 + hi * 8);
    s8v vf11 = *(const s8v*)(Vt + (long)(32 + l31) * SS + kv0 + 16 + hi * 8);

    float a[16];
#pragma unroll
    for (int r = 0; r < 16; ++r) a[r] = S[r];
    if (kv0 == q0) {  // boundary tile: keep iff kv row <= q col
#pragma unroll
      for (int r = 0; r < 16; ++r) {
        const int row = (r & 3) + 8 * (r >> 2) + 4 * hi;
        a[r] = (row <= l31) ? a[r] : -1e30f;
      }
    }
    // row max: 15 in-lane + 1 cross-half
    float mloc = a[0];
#pragma unroll
    for (int r = 1; r < 16; ++r) mloc = fmaxf(mloc, a[r]);
    mloc = fmaxf(mloc, __shfl_xor(mloc, 32));
    if (__any(mloc > m_run + 8.f)) {   // defer-max (THR=8, exp2 domain)
      const float mnew = fmaxf(m_run, mloc);
      const float corr = fexp2(m_run - mnew);
      m_run = mnew;
      l_run *= corr;
#pragma unroll
      for (int r = 0; r < 16; ++r) { accO0[r] *= corr; accO1[r] *= corr; }
    }
    float p[16], sloc = 0.f;
#pragma unroll
    for (int r = 0; r < 16; ++r) {
      p[r] = fexp2(a[r] - m_run);
      sloc += p[r];
    }
    sloc += __shfl_xor(sloc, 32);
    l_run += sloc;

    // P -> B-frags. Lane holds rows (r&3)+8*(r>>2)+4*hi; B-frag ks needs
    // rows ks*16 + hi*8 + j. One cross-half exchange fills the gaps.
    const unsigned u0 = pk2bf(p[0],  p[1]),  u1 = pk2bf(p[2],  p[3]);
    const unsigned u2 = pk2bf(p[4],  p[5]),  u3 = pk2bf(p[6],  p[7]);
    const unsigned u4 = pk2bf(p[8],  p[9]),  u5 = pk2bf(p[10], p[11]);
    const unsigned u6 = pk2bf(p[12], p[13]), u7 = pk2bf(p[14], p[15]);
    const unsigned e0 = __shfl_xor(u0, 32), e1 = __shfl_xor(u1, 32);
    const unsigned e2 = __shfl_xor(u2, 32), e3 = __shfl_xor(u3, 32);
    const unsigned e4 = __shfl_xor(u4, 32), e5 = __shfl_xor(u5, 32);
    const unsigned e6 = __shfl_xor(u6, 32), e7 = __shfl_xor(u7, 32);
    const bool hih = (hi != 0);
    union { unsigned u[4]; s8v v; } P0, P1;
    P0.u[0] = hih ? e2 : u0;  P0.u[1] = hih ? e3 : u1;
    P0.u[2] = hih ? u2 : e0;  P0.u[3] = hih ? u3 : e1;
    P1.u[0] = hih ? e6 : u4;  P1.u[1] = hih ? e7 : u5;
    P1.u[2] = hih ? u6 : e4;  P1.u[3] = hih ? u7 : e5;

    // PV: O[d][q] += V[d][kv] * P[kv][q]
    accO0 = __builtin_amdgcn_mfma_f32_32x32x16_bf16(vf00, P0.v, accO0, 0, 0, 0);
    accO0 = __builtin_amdgcn_mfma_f32_32x32x16_bf16(vf01, P1.v, accO0, 0, 0, 0);
    accO1 = __builtin_amdgcn_mfma_f32_32x32x16_bf16(vf10, P0.v, accO1, 0, 0, 0);
    accO1 = __builtin_amdgcn_mfma_f32_32x32x16_bf16(vf11, P1.v, accO1, 0, 0, 0);
  }

  const float inv = 1.f / l_run;
  const int s = q0 + l31;
  unsigned short* orow = obuf + (long)(b * SS + s) * HH + h * HDIM;
#pragma unroll
  for (int g = 0; g < 4; ++g) {
    const int d0 = 8 * g + 4 * hi;
    ushort4 o0, o1;
    o0.x = f2bf(accO0[4 * g + 0] * inv);
    o0.y = f2bf(accO0[4 * g + 1] * inv);
    o0.z = f2bf(accO0[4 * g + 2] * inv);
    o0.w = f2bf(accO0[4 * g + 3] * inv);
    o1.x = f2bf(accO1[4 * g + 0] * inv);
    o1.y = f2bf(accO1[4 * g + 1] * inv);
    o1.z = f2bf(accO1[4 * g + 2] * inv);
    o1.w = f2bf(accO1[4 * g + 3] * inv);
    *(ushort4*)(orow + d0)      = o0;
    *(ushort4*)(orow + 32 + d0) = o1;
  }
}

// ----------------- kernel 5: output projection -> fp32 d_out ----------------
__global__ __launch_bounds__(256) void out_gemm_kernel(
    const unsigned short* __restrict__ ob, const unsigned short* __restrict__ wot,
    float* __restrict__ out)
{
  const int lane = threadIdx.x & 63;
  const int wid  = threadIdx.x >> 6;
  const int l15 = lane & 15, hi = lane >> 4;
  const int m0 = blockIdx.x * 64 + wid * 16;
  const int n0 = blockIdx.y * 64;

  const f4v zero = {0.f, 0.f, 0.f, 0.f};
  f4v acc[4] = {zero, zero, zero, zero};

  for (int kk = 0; kk < 18; ++kk) {
    const int k0 = kk * 32 + hi * 8;
    s8v a = *(const s8v*)(ob + (long)(m0 + l15) * 576 + k0);
#pragma unroll
    for (int nb = 0; nb < 4; ++nb) {
      s8v b = *(const s8v*)(wot + (long)(n0 + nb * 16 + l15) * 576 + k0);
      acc[nb] = __builtin_amdgcn_mfma_f32_16x16x32_bf16(a, b, acc[nb], 0, 0, 0);
    }
  }
#pragma unroll
  for (int r = 0; r < 4; ++r) {
    const int row = m0 + hi * 4 + r;
#pragma unroll
    for (int nb = 0; nb < 4; ++nb) {
      out[(long)row * 576 + n0 + nb * 16 + l15] = acc[nb][r];
    }
  }
}

extern "C" void kernel_launch(void* const* d_in, const int* in_sizes, int n_in,
                              void* d_out, int out_size, void* d_ws, size_t ws_size,
                              hipStream_t stream) {
  const float* hs  = (const float*)d_in[0];
  const float* rot = (const float*)d_in[2];
  const float* wq  = (const float*)d_in[3];
  const float* wk  = (const float*)d_in[4];
  const float* wv  = (const float*)d_in[5];
  const float* wo  = (const float*)d_in[6];
  float* out = (float*)d_out;

  char* ws = (char*)d_ws;
  unsigned short* xb    = (unsigned short*)(ws + 0);          // 9,437,184
  unsigned short* wqkvt = (unsigned short*)(ws + 9437184);    // 1,105,920
  unsigned short* wot   = (unsigned short*)(ws + 10543104);   //   663,552
  unsigned short* qb    = (unsigned short*)(ws + 11206656);   // 9,437,184
  unsigned short* kb    = (unsigned short*)(ws + 20643840);   // 3,145,728
  unsigned short* vt    = (unsigned short*)(ws + 23789568);   // 3,145,728
  unsigned short* obuf  = (unsigned short*)(ws + 26935296);   // 9,437,184 -> 36,372,480

  cast_x_kernel<<<4608, 256, 0, stream>>>(hs, xb);
  pack_w_kernel<<<3456, 256, 0, stream>>>(wq, wk, wv, wo, wqkvt, wot);
  qkv_gemm_kernel<<<dim3(128, 15), 256, 0, stream>>>(xb, wqkvt, rot, qb, kb, vt);
  flash32_kernel<<<1152, 128, 0, stream>>>(qb, kb, vt, obuf);
  out_gemm_kernel<<<dim3(128, 9), 256, 0, stream>>>(obuf, wot, out);
}

// Round 6
// 138.335 us; speedup vs baseline: 3.4494x; 1.7356x over previous
//
#include <hip/hip_runtime.h>
#include <hip/hip_bf16.h>

#define BB 4
#define SS 2048
#define HH 576
#define NHD 9
#define NKVH 3
#define HDIM 64

using s8v  = __attribute__((ext_vector_type(8))) short;
using f4v  = __attribute__((ext_vector_type(4))) float;
using f16v = __attribute__((ext_vector_type(16))) float;

__device__ __forceinline__ unsigned short f2bf(float f) {
  union { float f; unsigned u; } x; x.f = f;
  unsigned r = x.u + 0x7fffu + ((x.u >> 16) & 1u);
  return (unsigned short)(r >> 16);
}

__device__ __forceinline__ unsigned pk2bf(float lo, float hi) {
  union { __hip_bfloat162 h; unsigned u; } c;
  c.h = __float22bfloat162_rn(make_float2(lo, hi));
  return c.u;
}

__device__ __forceinline__ float fexp2(float x) {
#if __has_builtin(__builtin_amdgcn_exp2f)
  return __builtin_amdgcn_exp2f(x);
#else
  return exp2f(x);
#endif
}

// Q pre-scale: (1/sqrt(64)) * log2(e) -> softmax runs in exp2 domain
#define QSCALE 0.1803368867f

// ---------------- kernel 1: cast hidden_states fp32 -> bf16 ----------------
__global__ void cast_x_kernel(const float* __restrict__ hs, unsigned short* __restrict__ xb) {
  long i = (long)blockIdx.x * blockDim.x + threadIdx.x;
  long base = i * 4;
  float4 v = *(const float4*)(hs + base);
  ushort4 o;
  o.x = f2bf(v.x); o.y = f2bf(v.y); o.z = f2bf(v.z); o.w = f2bf(v.w);
  *(ushort4*)(xb + base) = o;
}

// ------------- kernel 2: pack weights -> bf16, transposed [n][k] -----------
__global__ void pack_w_kernel(const float* __restrict__ wq, const float* __restrict__ wk,
                              const float* __restrict__ wv, const float* __restrict__ wo,
                              unsigned short* __restrict__ wqkvt, unsigned short* __restrict__ wot) {
  int i = blockIdx.x * blockDim.x + threadIdx.x;
  if (i < 960 * 576) {
    int n = i / 576, k = i % 576;
    float val;
    if (n < 576)      val = wq[k * 576 + n];
    else if (n < 768) val = wk[k * 192 + (n - 576)];
    else              val = wv[k * 192 + (n - 768)];
    wqkvt[n * 576 + k] = f2bf(val);
  } else {
    int j = i - 960 * 576;
    int n = j / 576, k = j % 576;
    wot[n * 576 + k] = f2bf(wo[k * 576 + n]);
  }
}

// ======================= tiled GEMM core (shared fn) =======================
// BM=128, BN=64, BK=32, 256 thr = 4 waves. Wave w: rows m0+w*32..+32, all 64
// cols. LDS per buf: A[128][32] (8 KB) + B[64][32] (4 KB), XOR-swizzled;
// double-buffered (24 KB). Reg-staged: load(t+1) -> mfma(t) -> ds_write(t+1).
#define LDSBUF 12288

__device__ __forceinline__ void gemm_tile_core(char* lds,
    const unsigned short* __restrict__ Ag,   // A panel base: rows m0.., [576]
    const unsigned short* __restrict__ Bg,   // B panel base: rows n0.., [576]
    int tid, f4v acc[2][4])
{
  const int lane = tid & 63, wid = tid >> 6;
  const int l15 = lane & 15, hi = lane >> 4;
  const int r = tid >> 2, p = tid & 3;

  const unsigned short* sA0 = Ag + (long)r * 576 + p * 8;
  const unsigned short* sA1 = sA0 + (long)64 * 576;
  const unsigned short* sB  = Bg + (long)r * 576 + p * 8;
  const int dA0 = r * 64 + ((p ^ (r & 3)) * 16);
  const int dA1 = dA0 + 4096;
  const int dB  = 8192 + dA0;

  const int roff = (wid * 32 + l15) * 64 + ((hi ^ (l15 & 3)) * 16);
  const int boff = 8192 + l15 * 64 + ((hi ^ (l15 & 3)) * 16);

  s8v rA0 = *(const s8v*)(sA0);
  s8v rA1 = *(const s8v*)(sA1);
  s8v rB  = *(const s8v*)(sB);
  *(s8v*)(lds + dA0) = rA0;
  *(s8v*)(lds + dA1) = rA1;
  *(s8v*)(lds + dB)  = rB;
  __syncthreads();

  int cur = 0;
  for (int t = 0; t < 18; ++t) {
    if (t < 17) {
      rA0 = *(const s8v*)(sA0 + (t + 1) * 32);
      rA1 = *(const s8v*)(sA1 + (t + 1) * 32);
      rB  = *(const s8v*)(sB  + (t + 1) * 32);
    }
    {
      char* buf = lds + cur * LDSBUF;
      s8v af0 = *(const s8v*)(buf + roff);
      s8v af1 = *(const s8v*)(buf + roff + 16 * 64);
      s8v bf0 = *(const s8v*)(buf + boff);
      s8v bf1 = *(const s8v*)(buf + boff + 16 * 64);
      s8v bf2 = *(const s8v*)(buf + boff + 32 * 64);
      s8v bf3 = *(const s8v*)(buf + boff + 48 * 64);
      acc[0][0] = __builtin_amdgcn_mfma_f32_16x16x32_bf16(af0, bf0, acc[0][0], 0, 0, 0);
      acc[0][1] = __builtin_amdgcn_mfma_f32_16x16x32_bf16(af0, bf1, acc[0][1], 0, 0, 0);
      acc[0][2] = __builtin_amdgcn_mfma_f32_16x16x32_bf16(af0, bf2, acc[0][2], 0, 0, 0);
      acc[0][3] = __builtin_amdgcn_mfma_f32_16x16x32_bf16(af0, bf3, acc[0][3], 0, 0, 0);
      acc[1][0] = __builtin_amdgcn_mfma_f32_16x16x32_bf16(af1, bf0, acc[1][0], 0, 0, 0);
      acc[1][1] = __builtin_amdgcn_mfma_f32_16x16x32_bf16(af1, bf1, acc[1][1], 0, 0, 0);
      acc[1][2] = __builtin_amdgcn_mfma_f32_16x16x32_bf16(af1, bf2, acc[1][2], 0, 0, 0);
      acc[1][3] = __builtin_amdgcn_mfma_f32_16x16x32_bf16(af1, bf3, acc[1][3], 0, 0, 0);
    }
    if (t < 17) {
      char* nbuf = lds + (cur ^ 1) * LDSBUF;
      *(s8v*)(nbuf + dA0) = rA0;
      *(s8v*)(nbuf + dA1) = rA1;
      *(s8v*)(nbuf + dB)  = rB;
    }
    __syncthreads();
    cur ^= 1;
  }
}

// ---- kernel 3: QKV GEMM (tiled) + fused RoPE; writes Q,K,[Vt] bf16 --------
__global__ __launch_bounds__(256) void qkv_gemm_kernel(
    const unsigned short* __restrict__ xb, const unsigned short* __restrict__ wt,
    const float* __restrict__ rot,
    unsigned short* __restrict__ qbuf, unsigned short* __restrict__ kbuf,
    unsigned short* __restrict__ vtbuf)
{
  __shared__ char lds[2 * LDSBUF];
  const int tid = threadIdx.x;
  const int lane = tid & 63, wid = tid >> 6;
  const int l15 = lane & 15, hi = lane >> 4;
  const int m0 = blockIdx.x * 128;
  const int g  = blockIdx.y;   // 0..8 Q, 9..11 K, 12..14 V

  f4v acc[2][4] = {};
  gemm_tile_core(lds, xb + (long)m0 * 576, wt + (long)(g * 64) * 576, tid, acc);

  const int rbase = m0 + wid * 32;
#pragma unroll
  for (int fm = 0; fm < 2; ++fm) {
#pragma unroll
    for (int rr = 0; rr < 4; ++rr) {
      const int row = rbase + fm * 16 + hi * 4 + rr;
      const int b = row >> 11, s = row & (SS - 1);
      if (g < 12) {  // RoPE: pairs (fn, fn+2) same lane
#pragma unroll
        for (int fn = 0; fn < 2; ++fn) {
          const int d = fn * 16 + l15;
          const float sn = rot[s * 64 + d];
          const float cs = rot[s * 64 + 32 + d];
          const float x1 = acc[fm][fn][rr];
          const float x2 = acc[fm][fn + 2][rr];
          acc[fm][fn][rr]     = x1 * cs - x2 * sn;
          acc[fm][fn + 2][rr] = x1 * sn + x2 * cs;
        }
      }
      if (g < 9) {
        unsigned short* dst = qbuf + ((long)((b * NHD + g) * SS + s)) * HDIM;
#pragma unroll
        for (int fn = 0; fn < 4; ++fn)
          dst[fn * 16 + l15] = f2bf(acc[fm][fn][rr] * QSCALE);
      } else if (g < 12) {
        unsigned short* dst = kbuf + ((long)((b * NKVH + (g - 9)) * SS + s)) * HDIM;
#pragma unroll
        for (int fn = 0; fn < 4; ++fn)
          dst[fn * 16 + l15] = f2bf(acc[fm][fn][rr]);
      } else {
        const int h = g - 12;
#pragma unroll
        for (int fn = 0; fn < 4; ++fn) {
          const int d = fn * 16 + l15;
          vtbuf[((long)((b * NKVH + h) * HDIM + d)) * SS + s] = f2bf(acc[fm][fn][rr]);
        }
      }
    }
  }
}

// --------------- kernel 5: output projection (tiled) -> fp32 ---------------
__global__ __launch_bounds__(256) void out_gemm_kernel(
    const unsigned short* __restrict__ ob, const unsigned short* __restrict__ wot,
    float* __restrict__ out)
{
  __shared__ char lds[2 * LDSBUF];
  const int tid = threadIdx.x;
  const int lane = tid & 63, wid = tid >> 6;
  const int l15 = lane & 15, hi = lane >> 4;
  const int m0 = blockIdx.x * 128;
  const int n0 = blockIdx.y * 64;

  f4v acc[2][4] = {};
  gemm_tile_core(lds, ob + (long)m0 * 576, wot + (long)n0 * 576, tid, acc);

  const int rbase = m0 + wid * 32;
#pragma unroll
  for (int fm = 0; fm < 2; ++fm)
#pragma unroll
    for (int rr = 0; rr < 4; ++rr) {
      const int row = rbase + fm * 16 + hi * 4 + rr;
#pragma unroll
      for (int fn = 0; fn < 4; ++fn)
        out[(long)row * 576 + n0 + fn * 16 + l15] = acc[fm][fn][rr];
    }
}

// ------ kernel 4: flash attention, 32x32x16 MFMA, swapped QK^T (R4) --------
__global__ __launch_bounds__(128) void flash32_kernel(
    const unsigned short* __restrict__ qbuf, const unsigned short* __restrict__ kbuf,
    const unsigned short* __restrict__ vtbuf, unsigned short* __restrict__ obuf)
{
  const int lane = threadIdx.x & 63, wid = threadIdx.x >> 6;
  const int l31 = lane & 31, hi = lane >> 5;
  const int widx = blockIdx.x * 2 + wid;
  const int qs = 63 - widx / 36;
  const int bh = widx % 36;
  const int q0 = qs * 32;
  const int b = bh / NHD, h = bh % NHD;
  const int hkv = h / 3;

  const unsigned short* Q  = qbuf + ((long)(b * NHD + h) * SS) * HDIM;
  const unsigned short* K  = kbuf + ((long)(b * NKVH + hkv) * SS) * HDIM;
  const unsigned short* Vt = vtbuf + ((long)(b * NKVH + hkv) * HDIM) * SS;

  s8v qf[4];
#pragma unroll
  for (int ks = 0; ks < 4; ++ks)
    qf[ks] = *(const s8v*)(Q + (long)(q0 + l31) * HDIM + ks * 16 + hi * 8);

  f16v accO0 = {}, accO1 = {};
  float m_run = -1e30f, l_run = 0.f;

  s8v kf[4];
#pragma unroll
  for (int ks = 0; ks < 4; ++ks)
    kf[ks] = *(const s8v*)(K + (long)(l31) * HDIM + ks * 16 + hi * 8);

  for (int kv0 = 0; kv0 <= q0; kv0 += 32) {
    f16v S = {};
    S = __builtin_amdgcn_mfma_f32_32x32x16_bf16(kf[0], qf[0], S, 0, 0, 0);
    S = __builtin_amdgcn_mfma_f32_32x32x16_bf16(kf[1], qf[1], S, 0, 0, 0);
    S = __builtin_amdgcn_mfma_f32_32x32x16_bf16(kf[2], qf[2], S, 0, 0, 0);
    S = __builtin_amdgcn_mfma_f32_32x32x16_bf16(kf[3], qf[3], S, 0, 0, 0);

    {
      const unsigned short* Kn = K + (long)(kv0 + 32 + l31) * HDIM;
#pragma unroll
      for (int ks = 0; ks < 4; ++ks)
        kf[ks] = *(const s8v*)(Kn + ks * 16 + hi * 8);
    }
    s8v vf00 = *(const s8v*)(Vt + (long)(l31) * SS      + kv0 + hi * 8);
    s8v vf01 = *(const s8v*)(Vt + (long)(l31) * SS      + kv0 + 16 + hi * 8);
    s8v vf10 = *(const s8v*)(Vt + (long)(32 + l31) * SS + kv0 + hi * 8);
    s8v vf11 = *(const s8v*)(Vt + (long)(32 + l31) * SS + kv0 + 16 + hi * 8);

    float a[16];
#pragma unroll
    for (int r = 0; r < 16; ++r) a[r] = S[r];
    if (kv0 == q0) {
#pragma unroll
      for (int r = 0; r < 16; ++r) {
        const int row = (r & 3) + 8 * (r >> 2) + 4 * hi;
        a[r] = (row <= l31) ? a[r] : -1e30f;
      }
    }
    float mloc = a[0];
#pragma unroll
    for (int r = 1; r < 16; ++r) mloc = fmaxf(mloc, a[r]);
    mloc = fmaxf(mloc, __shfl_xor(mloc, 32));
    if (__any(mloc > m_run + 8.f)) {
      const float mnew = fmaxf(m_run, mloc);
      const float corr = fexp2(m_run - mnew);
      m_run = mnew;
      l_run *= corr;
#pragma unroll
      for (int r = 0; r < 16; ++r) { accO0[r] *= corr; accO1[r] *= corr; }
    }
    float p[16], sloc = 0.f;
#pragma unroll
    for (int r = 0; r < 16; ++r) {
      p[r] = fexp2(a[r] - m_run);
      sloc += p[r];
    }
    sloc += __shfl_xor(sloc, 32);
    l_run += sloc;

    const unsigned u0 = pk2bf(p[0],  p[1]),  u1 = pk2bf(p[2],  p[3]);
    const unsigned u2 = pk2bf(p[4],  p[5]),  u3 = pk2bf(p[6],  p[7]);
    const unsigned u4 = pk2bf(p[8],  p[9]),  u5 = pk2bf(p[10], p[11]);
    const unsigned u6 = pk2bf(p[12], p[13]), u7 = pk2bf(p[14], p[15]);
    const unsigned e0 = __shfl_xor(u0, 32), e1 = __shfl_xor(u1, 32);
    const unsigned e2 = __shfl_xor(u2, 32), e3 = __shfl_xor(u3, 32);
    const unsigned e4 = __shfl_xor(u4, 32), e5 = __shfl_xor(u5, 32);
    const unsigned e6 = __shfl_xor(u6, 32), e7 = __shfl_xor(u7, 32);
    const bool hih = (hi != 0);
    union { unsigned u[4]; s8v v; } P0, P1;
    P0.u[0] = hih ? e2 : u0;  P0.u[1] = hih ? e3 : u1;
    P0.u[2] = hih ? u2 : e0;  P0.u[3] = hih ? u3 : e1;
    P1.u[0] = hih ? e6 : u4;  P1.u[1] = hih ? e7 : u5;
    P1.u[2] = hih ? u6 : e4;  P1.u[3] = hih ? u7 : e5;

    accO0 = __builtin_amdgcn_mfma_f32_32x32x16_bf16(vf00, P0.v, accO0, 0, 0, 0);
    accO0 = __builtin_amdgcn_mfma_f32_32x32x16_bf16(vf01, P1.v, accO0, 0, 0, 0);
    accO1 = __builtin_amdgcn_mfma_f32_32x32x16_bf16(vf10, P0.v, accO1, 0, 0, 0);
    accO1 = __builtin_amdgcn_mfma_f32_32x32x16_bf16(vf11, P1.v, accO1, 0, 0, 0);
  }

  const float inv = 1.f / l_run;
  const int s = q0 + l31;
  unsigned short* orow = obuf + (long)(b * SS + s) * HH + h * HDIM;
#pragma unroll
  for (int g = 0; g < 4; ++g) {
    const int d0 = 8 * g + 4 * hi;
    ushort4 o0, o1;
    o0.x = f2bf(accO0[4 * g + 0] * inv);
    o0.y = f2bf(accO0[4 * g + 1] * inv);
    o0.z = f2bf(accO0[4 * g + 2] * inv);
    o0.w = f2bf(accO0[4 * g + 3] * inv);
    o1.x = f2bf(accO1[4 * g + 0] * inv);
    o1.y = f2bf(accO1[4 * g + 1] * inv);
    o1.z = f2bf(accO1[4 * g + 2] * inv);
    o1.w = f2bf(accO1[4 * g + 3] * inv);
    *(ushort4*)(orow + d0)      = o0;
    *(ushort4*)(orow + 32 + d0) = o1;
  }
}

extern "C" void kernel_launch(void* const* d_in, const int* in_sizes, int n_in,
                              void* d_out, int out_size, void* d_ws, size_t ws_size,
                              hipStream_t stream) {
  const float* hs  = (const float*)d_in[0];
  const float* rot = (const float*)d_in[2];
  const float* wq  = (const float*)d_in[3];
  const float* wk  = (const float*)d_in[4];
  const float* wv  = (const float*)d_in[5];
  const float* wo  = (const float*)d_in[6];
  float* out = (float*)d_out;

  char* ws = (char*)d_ws;
  unsigned short* xb    = (unsigned short*)(ws + 0);          // 9,437,184
  unsigned short* wqkvt = (unsigned short*)(ws + 9437184);    // 1,105,920
  unsigned short* wot   = (unsigned short*)(ws + 10543104);   //   663,552
  unsigned short* qb    = (unsigned short*)(ws + 11206656);   // 9,437,184
  unsigned short* kb    = (unsigned short*)(ws + 20643840);   // 3,145,728
  unsigned short* vt    = (unsigned short*)(ws + 23789568);   // 3,145,728
  unsigned short* obuf  = (unsigned short*)(ws + 26935296);   // 9,437,184 -> 36,372,480

  cast_x_kernel<<<4608, 256, 0, stream>>>(hs, xb);
  pack_w_kernel<<<3456, 256, 0, stream>>>(wq, wk, wv, wo, wqkvt, wot);
  qkv_gemm_kernel<<<dim3(64, 15), 256, 0, stream>>>(xb, wqkvt, rot, qb, kb, vt);
  flash32_kernel<<<1152, 128, 0, stream>>>(qb, kb, vt, obuf);
  out_gemm_kernel<<<dim3(64, 9), 256, 0, stream>>>(obuf, wot, out);
}

// Round 7
// 131.256 us; speedup vs baseline: 3.6354x; 1.0539x over previous
//
#include <hip/hip_runtime.h>
#include <hip/hip_bf16.h>

#define BB 4
#define SS 2048
#define HH 576
#define NHD 9
#define NKVH 3
#define HDIM 64

using s8v  = __attribute__((ext_vector_type(8))) short;
using f4v  = __attribute__((ext_vector_type(4))) float;
using f16v = __attribute__((ext_vector_type(16))) float;

__device__ __forceinline__ unsigned short f2bf(float f) {
  union { float f; unsigned u; } x; x.f = f;
  unsigned r = x.u + 0x7fffu + ((x.u >> 16) & 1u);
  return (unsigned short)(r >> 16);
}

__device__ __forceinline__ unsigned pk2bf(float lo, float hi) {
  union { __hip_bfloat162 h; unsigned u; } c;
  c.h = __float22bfloat162_rn(make_float2(lo, hi));
  return c.u;
}

__device__ __forceinline__ float fexp2(float x) {
#if __has_builtin(__builtin_amdgcn_exp2f)
  return __builtin_amdgcn_exp2f(x);
#else
  return exp2f(x);
#endif
}

// Q pre-scale: (1/sqrt(64)) * log2(e) -> softmax runs in exp2 domain
#define QSCALE 0.1803368867f

// ---------------- kernel 1: cast hidden_states fp32 -> bf16 ----------------
__global__ void cast_x_kernel(const float* __restrict__ hs, unsigned short* __restrict__ xb) {
  long i = (long)blockIdx.x * blockDim.x + threadIdx.x;
  long base = i * 4;
  float4 v = *(const float4*)(hs + base);
  ushort4 o;
  o.x = f2bf(v.x); o.y = f2bf(v.y); o.z = f2bf(v.z); o.w = f2bf(v.w);
  *(ushort4*)(xb + base) = o;
}

// ------------- kernel 2: pack weights -> bf16, transposed [n][k] -----------
__global__ void pack_w_kernel(const float* __restrict__ wq, const float* __restrict__ wk,
                              const float* __restrict__ wv, const float* __restrict__ wo,
                              unsigned short* __restrict__ wqkvt, unsigned short* __restrict__ wot) {
  int i = blockIdx.x * blockDim.x + threadIdx.x;
  if (i < 960 * 576) {
    int n = i / 576, k = i % 576;
    float val;
    if (n < 576)      val = wq[k * 576 + n];
    else if (n < 768) val = wk[k * 192 + (n - 576)];
    else              val = wv[k * 192 + (n - 768)];
    wqkvt[n * 576 + k] = f2bf(val);
  } else {
    int j = i - 960 * 576;
    int n = j / 576, k = j % 576;
    wot[n * 576 + k] = f2bf(wo[k * 576 + n]);
  }
}

// ======================= tiled GEMM core (shared fn) =======================
#define LDSBUF 12288

__device__ __forceinline__ void gemm_tile_core(char* lds,
    const unsigned short* __restrict__ Ag,
    const unsigned short* __restrict__ Bg,
    int tid, f4v acc[2][4])
{
  const int lane = tid & 63, wid = tid >> 6;
  const int l15 = lane & 15, hi = lane >> 4;
  const int r = tid >> 2, p = tid & 3;

  const unsigned short* sA0 = Ag + (long)r * 576 + p * 8;
  const unsigned short* sA1 = sA0 + (long)64 * 576;
  const unsigned short* sB  = Bg + (long)r * 576 + p * 8;
  const int dA0 = r * 64 + ((p ^ (r & 3)) * 16);
  const int dA1 = dA0 + 4096;
  const int dB  = 8192 + dA0;

  const int roff = (wid * 32 + l15) * 64 + ((hi ^ (l15 & 3)) * 16);
  const int boff = 8192 + l15 * 64 + ((hi ^ (l15 & 3)) * 16);

  s8v rA0 = *(const s8v*)(sA0);
  s8v rA1 = *(const s8v*)(sA1);
  s8v rB  = *(const s8v*)(sB);
  *(s8v*)(lds + dA0) = rA0;
  *(s8v*)(lds + dA1) = rA1;
  *(s8v*)(lds + dB)  = rB;
  __syncthreads();

  int cur = 0;
  for (int t = 0; t < 18; ++t) {
    if (t < 17) {
      rA0 = *(const s8v*)(sA0 + (t + 1) * 32);
      rA1 = *(const s8v*)(sA1 + (t + 1) * 32);
      rB  = *(const s8v*)(sB  + (t + 1) * 32);
    }
    {
      char* buf = lds + cur * LDSBUF;
      s8v af0 = *(const s8v*)(buf + roff);
      s8v af1 = *(const s8v*)(buf + roff + 16 * 64);
      s8v bf0 = *(const s8v*)(buf + boff);
      s8v bf1 = *(const s8v*)(buf + boff + 16 * 64);
      s8v bf2 = *(const s8v*)(buf + boff + 32 * 64);
      s8v bf3 = *(const s8v*)(buf + boff + 48 * 64);
      acc[0][0] = __builtin_amdgcn_mfma_f32_16x16x32_bf16(af0, bf0, acc[0][0], 0, 0, 0);
      acc[0][1] = __builtin_amdgcn_mfma_f32_16x16x32_bf16(af0, bf1, acc[0][1], 0, 0, 0);
      acc[0][2] = __builtin_amdgcn_mfma_f32_16x16x32_bf16(af0, bf2, acc[0][2], 0, 0, 0);
      acc[0][3] = __builtin_amdgcn_mfma_f32_16x16x32_bf16(af0, bf3, acc[0][3], 0, 0, 0);
      acc[1][0] = __builtin_amdgcn_mfma_f32_16x16x32_bf16(af1, bf0, acc[1][0], 0, 0, 0);
      acc[1][1] = __builtin_amdgcn_mfma_f32_16x16x32_bf16(af1, bf1, acc[1][1], 0, 0, 0);
      acc[1][2] = __builtin_amdgcn_mfma_f32_16x16x32_bf16(af1, bf2, acc[1][2], 0, 0, 0);
      acc[1][3] = __builtin_amdgcn_mfma_f32_16x16x32_bf16(af1, bf3, acc[1][3], 0, 0, 0);
    }
    if (t < 17) {
      char* nbuf = lds + (cur ^ 1) * LDSBUF;
      *(s8v*)(nbuf + dA0) = rA0;
      *(s8v*)(nbuf + dA1) = rA1;
      *(s8v*)(nbuf + dB)  = rB;
    }
    __syncthreads();
    cur ^= 1;
  }
}

// ---- kernel 3: QKV GEMM (tiled) + fused RoPE; writes Q,K,[Vt] bf16 --------
__global__ __launch_bounds__(256) void qkv_gemm_kernel(
    const unsigned short* __restrict__ xb, const unsigned short* __restrict__ wt,
    const float* __restrict__ rot,
    unsigned short* __restrict__ qbuf, unsigned short* __restrict__ kbuf,
    unsigned short* __restrict__ vtbuf)
{
  __shared__ char lds[2 * LDSBUF];
  const int tid = threadIdx.x;
  const int lane = tid & 63, wid = tid >> 6;
  const int l15 = lane & 15, hi = lane >> 4;
  const int m0 = blockIdx.x * 128;
  const int g  = blockIdx.y;   // 0..8 Q, 9..11 K, 12..14 V

  f4v acc[2][4] = {};
  gemm_tile_core(lds, xb + (long)m0 * 576, wt + (long)(g * 64) * 576, tid, acc);

  const int rbase = m0 + wid * 32;
#pragma unroll
  for (int fm = 0; fm < 2; ++fm) {
#pragma unroll
    for (int rr = 0; rr < 4; ++rr) {
      const int row = rbase + fm * 16 + hi * 4 + rr;
      const int b = row >> 11, s = row & (SS - 1);
      if (g < 12) {
#pragma unroll
        for (int fn = 0; fn < 2; ++fn) {
          const int d = fn * 16 + l15;
          const float sn = rot[s * 64 + d];
          const float cs = rot[s * 64 + 32 + d];
          const float x1 = acc[fm][fn][rr];
          const float x2 = acc[fm][fn + 2][rr];
          acc[fm][fn][rr]     = x1 * cs - x2 * sn;
          acc[fm][fn + 2][rr] = x1 * sn + x2 * cs;
        }
      }
      if (g < 9) {
        unsigned short* dst = qbuf + ((long)((b * NHD + g) * SS + s)) * HDIM;
#pragma unroll
        for (int fn = 0; fn < 4; ++fn)
          dst[fn * 16 + l15] = f2bf(acc[fm][fn][rr] * QSCALE);
      } else if (g < 12) {
        unsigned short* dst = kbuf + ((long)((b * NKVH + (g - 9)) * SS + s)) * HDIM;
#pragma unroll
        for (int fn = 0; fn < 4; ++fn)
          dst[fn * 16 + l15] = f2bf(acc[fm][fn][rr]);
      } else {
        const int h = g - 12;
#pragma unroll
        for (int fn = 0; fn < 4; ++fn) {
          const int d = fn * 16 + l15;
          vtbuf[((long)((b * NKVH + h) * HDIM + d)) * SS + s] = f2bf(acc[fm][fn][rr]);
        }
      }
    }
  }
}

// --------------- kernel 5: output projection (tiled) -> fp32 ---------------
__global__ __launch_bounds__(256) void out_gemm_kernel(
    const unsigned short* __restrict__ ob, const unsigned short* __restrict__ wot,
    float* __restrict__ out)
{
  __shared__ char lds[2 * LDSBUF];
  const int tid = threadIdx.x;
  const int lane = tid & 63, wid = tid >> 6;
  const int l15 = lane & 15, hi = lane >> 4;
  const int m0 = blockIdx.x * 128;
  const int n0 = blockIdx.y * 64;

  f4v acc[2][4] = {};
  gemm_tile_core(lds, ob + (long)m0 * 576, wot + (long)n0 * 576, tid, acc);

  const int rbase = m0 + wid * 32;
#pragma unroll
  for (int fm = 0; fm < 2; ++fm)
#pragma unroll
    for (int rr = 0; rr < 4; ++rr) {
      const int row = rbase + fm * 16 + hi * 4 + rr;
#pragma unroll
      for (int fn = 0; fn < 4; ++fn)
        out[(long)row * 576 + n0 + fn * 16 + l15] = acc[fm][fn][rr];
    }
}

// ------ kernel 4: flash, 32x32x16 swapped QK^T + 4-way block split-KV ------
// Block = 256 thr = 4 waves = one (bh, 32-row q-tile). Wave w handles KV
// tiles [nt*w/4, nt*(w+1)/4); partials (m,l,O) merged via LDS. No global
// partials -> no extra L2 streams (R2 lesson).
__global__ __launch_bounds__(256, 4) void flash32_kernel(
    const unsigned short* __restrict__ qbuf, const unsigned short* __restrict__ kbuf,
    const unsigned short* __restrict__ vtbuf, unsigned short* __restrict__ obuf)
{
  __shared__ float Osh[4][64 * 32];   // [wave][d][q] f32
  __shared__ float mlsh[4][2][32];    // [wave][m|l][q]

  const int tid = threadIdx.x;
  const int lane = tid & 63, wv = tid >> 6;
  const int l31 = lane & 31, hi = lane >> 5;
  const int bid = blockIdx.x;               // 0..2303
  const int qs = 63 - bid / 36;             // descending work
  const int bh = bid % 36;
  const int q0 = qs * 32;
  const int b = bh / NHD, h = bh % NHD;
  const int hkv = h / 3;

  const int nt = qs + 1;
  const int ts = (nt * wv) >> 2;
  const int te = (nt * (wv + 1)) >> 2;

  const unsigned short* Q  = qbuf + ((long)(b * NHD + h) * SS) * HDIM;
  const unsigned short* K  = kbuf + ((long)(b * NKVH + hkv) * SS) * HDIM;
  const unsigned short* Vt = vtbuf + ((long)(b * NKVH + hkv) * HDIM) * SS;

  f16v accO0 = {}, accO1 = {};
  float m_run = -1e30f, l_run = 0.f;

  if (te > ts) {
    s8v qf[4];
#pragma unroll
    for (int ks = 0; ks < 4; ++ks)
      qf[ks] = *(const s8v*)(Q + (long)(q0 + l31) * HDIM + ks * 16 + hi * 8);

    s8v kf[4];
#pragma unroll
    for (int ks = 0; ks < 4; ++ks)
      kf[ks] = *(const s8v*)(K + (long)(ts * 32 + l31) * HDIM + ks * 16 + hi * 8);

    for (int t = ts; t < te; ++t) {
      const int kv0 = t * 32;
      f16v S = {};
      S = __builtin_amdgcn_mfma_f32_32x32x16_bf16(kf[0], qf[0], S, 0, 0, 0);
      S = __builtin_amdgcn_mfma_f32_32x32x16_bf16(kf[1], qf[1], S, 0, 0, 0);
      S = __builtin_amdgcn_mfma_f32_32x32x16_bf16(kf[2], qf[2], S, 0, 0, 0);
      S = __builtin_amdgcn_mfma_f32_32x32x16_bf16(kf[3], qf[3], S, 0, 0, 0);

      {  // prefetch next K tile (over-read stays inside workspace)
        const unsigned short* Kn = K + (long)(kv0 + 32 + l31) * HDIM;
#pragma unroll
        for (int ks = 0; ks < 4; ++ks)
          kf[ks] = *(const s8v*)(Kn + ks * 16 + hi * 8);
      }
      s8v vf00 = *(const s8v*)(Vt + (long)(l31) * SS      + kv0 + hi * 8);
      s8v vf01 = *(const s8v*)(Vt + (long)(l31) * SS      + kv0 + 16 + hi * 8);
      s8v vf10 = *(const s8v*)(Vt + (long)(32 + l31) * SS + kv0 + hi * 8);
      s8v vf11 = *(const s8v*)(Vt + (long)(32 + l31) * SS + kv0 + 16 + hi * 8);

      if (kv0 == q0) {  // boundary tile: keep iff kv row <= q col
#pragma unroll
        for (int r = 0; r < 16; ++r) {
          const int row = (r & 3) + 8 * (r >> 2) + 4 * hi;
          S[r] = (row <= l31) ? S[r] : -1e30f;
        }
      }
      float mloc = S[0];
#pragma unroll
      for (int r = 1; r < 16; ++r) mloc = fmaxf(mloc, S[r]);
      mloc = fmaxf(mloc, __shfl_xor(mloc, 32));
      if (__any(mloc > m_run + 8.f)) {   // defer-max (THR=8, exp2 domain)
        const float mnew = fmaxf(m_run, mloc);
        const float corr = fexp2(m_run - mnew);
        m_run = mnew;
        l_run *= corr;
#pragma unroll
        for (int r = 0; r < 16; ++r) { accO0[r] *= corr; accO1[r] *= corr; }
      }
      float p[16], sloc = 0.f;
#pragma unroll
      for (int r = 0; r < 16; ++r) {
        p[r] = fexp2(S[r] - m_run);
        sloc += p[r];
      }
      sloc += __shfl_xor(sloc, 32);
      l_run += sloc;

      const unsigned u0 = pk2bf(p[0],  p[1]),  u1 = pk2bf(p[2],  p[3]);
      const unsigned u2 = pk2bf(p[4],  p[5]),  u3 = pk2bf(p[6],  p[7]);
      const unsigned u4 = pk2bf(p[8],  p[9]),  u5 = pk2bf(p[10], p[11]);
      const unsigned u6 = pk2bf(p[12], p[13]), u7 = pk2bf(p[14], p[15]);
      const unsigned e0 = __shfl_xor(u0, 32), e1 = __shfl_xor(u1, 32);
      const unsigned e2 = __shfl_xor(u2, 32), e3 = __shfl_xor(u3, 32);
      const unsigned e4 = __shfl_xor(u4, 32), e5 = __shfl_xor(u5, 32);
      const unsigned e6 = __shfl_xor(u6, 32), e7 = __shfl_xor(u7, 32);
      const bool hih = (hi != 0);
      union { unsigned u[4]; s8v v; } P0, P1;
      P0.u[0] = hih ? e2 : u0;  P0.u[1] = hih ? e3 : u1;
      P0.u[2] = hih ? u2 : e0;  P0.u[3] = hih ? u3 : e1;
      P1.u[0] = hih ? e6 : u4;  P1.u[1] = hih ? e7 : u5;
      P1.u[2] = hih ? u6 : e4;  P1.u[3] = hih ? u7 : e5;

      accO0 = __builtin_amdgcn_mfma_f32_32x32x16_bf16(vf00, P0.v, accO0, 0, 0, 0);
      accO0 = __builtin_amdgcn_mfma_f32_32x32x16_bf16(vf01, P1.v, accO0, 0, 0, 0);
      accO1 = __builtin_amdgcn_mfma_f32_32x32x16_bf16(vf10, P0.v, accO1, 0, 0, 0);
      accO1 = __builtin_amdgcn_mfma_f32_32x32x16_bf16(vf11, P1.v, accO1, 0, 0, 0);
    }
  }

  // ---- stage partials to LDS: O[d][q] (lanes stride-1 in q, conflict-free)
  {
    float* Ow = &Osh[wv][0];
#pragma unroll
    for (int g = 0; g < 4; ++g) {
#pragma unroll
      for (int j = 0; j < 4; ++j) {
        const int d0 = (g << 3) + (hi << 2) + j;
        Ow[d0 * 32 + l31]        = accO0[4 * g + j];
        Ow[(32 + d0) * 32 + l31] = accO1[4 * g + j];
      }
    }
    if (hi == 0) { mlsh[wv][0][l31] = m_run; mlsh[wv][1][l31] = l_run; }
  }
  __syncthreads();

  // ---- combine: thread (q = tid&31, d = (tid>>5)*8 .. +8)
  {
    const int q = tid & 31;
    const int d0 = (tid >> 5) * 8;
    float m[4], l[4];
#pragma unroll
    for (int w = 0; w < 4; ++w) { m[w] = mlsh[w][0][q]; l[w] = mlsh[w][1][q]; }
    const float M = fmaxf(fmaxf(m[0], m[1]), fmaxf(m[2], m[3]));
    float wg[4], L = 0.f;
#pragma unroll
    for (int w = 0; w < 4; ++w) { wg[w] = fexp2(m[w] - M); L += l[w] * wg[w]; }
    const float inv = 1.f / L;
    union { unsigned short s[8]; ushort4 v[2]; } ou;
#pragma unroll
    for (int j = 0; j < 8; ++j) {
      const int d = d0 + j;
      const float o_ = Osh[0][d * 32 + q] * wg[0] + Osh[1][d * 32 + q] * wg[1]
                     + Osh[2][d * 32 + q] * wg[2] + Osh[3][d * 32 + q] * wg[3];
      ou.s[j] = f2bf(o_ * inv);
    }
    unsigned short* orow = obuf + (long)(b * SS + q0 + q) * HH + h * HDIM + d0;
    *(ushort4*)(orow)     = ou.v[0];
    *(ushort4*)(orow + 4) = ou.v[1];
  }
}

extern "C" void kernel_launch(void* const* d_in, const int* in_sizes, int n_in,
                              void* d_out, int out_size, void* d_ws, size_t ws_size,
                              hipStream_t stream) {
  const float* hs  = (const float*)d_in[0];
  const float* rot = (const float*)d_in[2];
  const float* wq  = (const float*)d_in[3];
  const float* wk  = (const float*)d_in[4];
  const float* wv  = (const float*)d_in[5];
  const float* wo  = (const float*)d_in[6];
  float* out = (float*)d_out;

  char* ws = (char*)d_ws;
  unsigned short* xb    = (unsigned short*)(ws + 0);          // 9,437,184
  unsigned short* wqkvt = (unsigned short*)(ws + 9437184);    // 1,105,920
  unsigned short* wot   = (unsigned short*)(ws + 10543104);   //   663,552
  unsigned short* qb    = (unsigned short*)(ws + 11206656);   // 9,437,184
  unsigned short* kb    = (unsigned short*)(ws + 20643840);   // 3,145,728
  unsigned short* vt    = (unsigned short*)(ws + 23789568);   // 3,145,728
  unsigned short* obuf  = (unsigned short*)(ws + 26935296);   // 9,437,184 -> 36,372,480

  cast_x_kernel<<<4608, 256, 0, stream>>>(hs, xb);
  pack_w_kernel<<<3456, 256, 0, stream>>>(wq, wk, wv, wo, wqkvt, wot);
  qkv_gemm_kernel<<<dim3(64, 15), 256, 0, stream>>>(xb, wqkvt, rot, qb, kb, vt);
  flash32_kernel<<<2304, 256, 0, stream>>>(qb, kb, vt, obuf);
  out_gemm_kernel<<<dim3(64, 9), 256, 0, stream>>>(obuf, wot, out);
}